// Round 7
// baseline (441.533 us; speedup 1.0000x reference)
//
#include <hip/hip_runtime.h>

#define HH 512
#define WW 512
#define SS (HH * WW)          // elements per plane (2^18)
#define P16N (16 * SS)        // 16 planes (2^22)

constexpr float FINF = 3.402823466e38f;

__device__ __forceinline__ int lswz(int j) { return j + (j >> 3); }

__device__ __forceinline__ float gray1(float r, float g, float b) {
    return 0.299f * r + 0.587f * g + 0.114f * b;
}

// ---------------- grad (gray fused, both dirs, 4 px/thread) ----------------
// dirsel: 2 = write gx->plane gxp0+img and gy->plane gyp0+img; 0 = gx only; 1 = gy only.
__global__ __launch_bounds__(256) void grad_both(const float* __restrict__ rgb,
                                                 float* __restrict__ dst,
                                                 int gxp0, int gyp0, int dirsel) {
    int sp = blockIdx.x * 256 + threadIdx.x;
    int idx = sp << 2;                             // [0, P16N)
    int img = idx >> 18;
    int pix = idx & (SS - 1);
    int i = pix >> 9, j0 = pix & (WW - 1);
    const float* p0 = rgb + (size_t)img * 3 * SS + pix;

    float4 r = *(const float4*)p0;
    float4 g = *(const float4*)(p0 + SS);
    float4 b = *(const float4*)(p0 + 2 * SS);
    float4 gy4 = make_float4(gray1(r.x, g.x, b.x), gray1(r.y, g.y, b.y),
                             gray1(r.z, g.z, b.z), gray1(r.w, g.w, b.w));
    if (dirsel != 1) {
        float grs = 0.f;
        if (j0 + 4 < WW) grs = gray1(p0[4], p0[SS + 4], p0[2 * SS + 4]);
        float4 gx = make_float4(gy4.x - gy4.y, gy4.y - gy4.z, gy4.z - gy4.w, gy4.w - grs);
        *(float4*)(dst + (size_t)(gxp0 + img) * SS + pix) = gx;
    }
    if (dirsel != 0) {
        float4 gd = make_float4(0.f, 0.f, 0.f, 0.f);
        if (i < HH - 1) {
            float4 r2 = *(const float4*)(p0 + WW);
            float4 g2 = *(const float4*)(p0 + SS + WW);
            float4 b2 = *(const float4*)(p0 + 2 * SS + WW);
            gd = make_float4(gray1(r2.x, g2.x, b2.x), gray1(r2.y, g2.y, b2.y),
                             gray1(r2.z, g2.z, b2.z), gray1(r2.w, g2.w, b2.w));
        }
        float4 gy = make_float4(gy4.x - gd.x, gy4.y - gd.y, gy4.z - gd.z, gy4.w - gd.w);
        *(float4*)(dst + (size_t)(gyp0 + img) * SS + pix) = gy;
    }
}

// Common tile geometry: TH=16 rows, TW=256 cols per block, 2R col halo in LDS.
#define TH 16
#define TW 256

// ---------------- dual max+min pool (column-first, tiled, skewed LDS) ----------------
template <bool PREABS, int R>
__global__ __launch_bounds__(256) void dual_pool(const float* __restrict__ src,
                                                 float* __restrict__ dmax,
                                                 float* __restrict__ dmin) {
    constexpr int TILESV = HH / TH, TILESH = WW / TW;
    constexpr int W = 2 * R + 1;
    constexpr int LW = TW + 2 * R;                 // loaded cols
    constexpr int PADL = LW + LW / 8 + 2;
    constexpr int NL2 = LW / 2;                    // float2 loader threads
    __shared__ float lmax[TH * PADL], lmin[TH * PADL];

    const int plane = blockIdx.x / (TILESV * TILESH);
    const int rem   = blockIdx.x % (TILESV * TILESH);
    const int i0    = (rem / TILESH) * TH;
    const int gj0   = (rem % TILESH) * TW;
    const size_t pbase = (size_t)plane * SS;
    const float* sp = src + pbase;
    const int t = threadIdx.x;

    if (t < NL2) {
        const int lj = 2 * t;
        const int gj = gj0 - R + lj;               // even; col pair fully in or out
        const bool cin = (unsigned)gj < (unsigned)WW;
        float2 rmx[W], rmn[W];
        auto ld = [&](int gi, float2& vx, float2& vn) {
            if (cin && (unsigned)gi < (unsigned)HH) {
                float2 v = *(const float2*)(sp + (size_t)gi * WW + gj);
                if (PREABS) { v.x = fabsf(v.x); v.y = fabsf(v.y); }
                vx = v; vn = v;
            } else {
                vx = make_float2(-FINF, -FINF); vn = make_float2(FINF, FINF);
            }
        };
        #pragma unroll
        for (int k = 0; k < W; ++k) ld(i0 - R + k, rmx[k], rmn[k]);
        const int ca = lswz(lj);                   // ca+1 == lswz(lj+1), lj even
        #pragma unroll
        for (int oi = 0; oi < TH; ++oi) {
            if (oi > 0) {
                #pragma unroll
                for (int k = 0; k < W - 1; ++k) { rmx[k] = rmx[k + 1]; rmn[k] = rmn[k + 1]; }
                ld(i0 + oi + R, rmx[W - 1], rmn[W - 1]);
            }
            float2 mx = rmx[0], mn = rmn[0];
            #pragma unroll
            for (int k = 1; k < W; ++k) {
                mx.x = fmaxf(mx.x, rmx[k].x); mx.y = fmaxf(mx.y, rmx[k].y);
                mn.x = fminf(mn.x, rmn[k].x); mn.y = fminf(mn.y, rmn[k].y);
            }
            lmax[oi * PADL + ca] = mx.x; lmax[oi * PADL + ca + 1] = mx.y;
            lmin[oi * PADL + ca] = mn.x; lmin[oi * PADL + ca + 1] = mn.y;
        }
    }
    __syncthreads();

    // Phase 2: spans of 8 outputs; sentinels already in LDS halo -> no bounds checks.
    for (int s = t; s < TH * (TW / 8); s += 256) {
        int rr = s >> 5, j0l = (s & 31) << 3;      // TW/8 == 32
        const float* rx = &lmax[rr * PADL];
        const float* rn = &lmin[rr * PADL];
        float vx[2 * R + 8], vn[2 * R + 8];
        #pragma unroll
        for (int k = 0; k < 2 * R + 8; ++k) {
            int lc = lswz(j0l + k);
            vx[k] = rx[lc];
            vn[k] = rn[lc];
        }
        float ox[8], on[8];
        #pragma unroll
        for (int d = 0; d < 8; ++d) {
            float mx = vx[d], mn = vn[d];
            #pragma unroll
            for (int k = 1; k <= 2 * R; ++k) { mx = fmaxf(mx, vx[d + k]); mn = fminf(mn, vn[d + k]); }
            ox[d] = mx; on[d] = mn;
        }
        size_t o = pbase + (size_t)(i0 + rr) * WW + gj0 + j0l;
        ((float4*)&dmax[o])[0] = make_float4(ox[0], ox[1], ox[2], ox[3]);
        ((float4*)&dmax[o])[1] = make_float4(ox[4], ox[5], ox[6], ox[7]);
        ((float4*)&dmin[o])[0] = make_float4(on[0], on[1], on[2], on[3]);
        ((float4*)&dmin[o])[1] = make_float4(on[4], on[5], on[6], on[7]);
    }
}

// ---------------- single avg pool, abs output (tiled) ----------------
template <int R>
__global__ __launch_bounds__(256) void avg_abs_pool(const float* __restrict__ src,
                                                    float* __restrict__ dst) {
    constexpr int TILESV = HH / TH, TILESH = WW / TW;
    constexpr int LW = TW + 2 * R;
    constexpr int PADL = LW + LW / 8 + 2;
    constexpr int NL2 = LW / 2;
    __shared__ float ls[TH * PADL];

    const int plane = blockIdx.x / (TILESV * TILESH);
    const int rem   = blockIdx.x % (TILESV * TILESH);
    const int i0    = (rem / TILESH) * TH;
    const int gj0   = (rem % TILESH) * TW;
    const size_t pbase = (size_t)plane * SS;
    const float* sp = src + pbase;
    const int t = threadIdx.x;

    if (t < NL2) {
        const int lj = 2 * t;
        const int gj = gj0 - R + lj;
        const bool cin = (unsigned)gj < (unsigned)WW;
        auto ld = [&](int gi) -> float2 {
            if (cin && (unsigned)gi < (unsigned)HH)
                return *(const float2*)(sp + (size_t)gi * WW + gj);
            return make_float2(0.f, 0.f);
        };
        float2 acc = make_float2(0.f, 0.f);
        #pragma unroll
        for (int k = -R; k <= R; ++k) { float2 v = ld(i0 + k); acc.x += v.x; acc.y += v.y; }
        const int ca = lswz(lj);
        ls[ca] = acc.x; ls[ca + 1] = acc.y;
        #pragma unroll
        for (int oi = 1; oi < TH; ++oi) {
            float2 a = ld(i0 + oi + R), s = ld(i0 + oi - R - 1);
            acc.x += a.x - s.x; acc.y += a.y - s.y;
            ls[oi * PADL + ca] = acc.x; ls[oi * PADL + ca + 1] = acc.y;
        }
    }
    __syncthreads();

    for (int s = t; s < TH * (TW / 8); s += 256) {
        int rr = s >> 5, j0l = (s & 31) << 3;
        int i = i0 + rr;
        int ch = min(i + R, HH - 1) - max(i - R, 0) + 1;
        const float* row = &ls[rr * PADL];
        float racc = 0.f;
        #pragma unroll
        for (int k = 0; k <= 2 * R; ++k) racc += row[lswz(j0l + k)];
        float ov[8];
        #pragma unroll
        for (int d = 0; d < 8; ++d) {
            if (d > 0) {
                racc += row[lswz(j0l + d + 2 * R)];
                racc -= row[lswz(j0l + d - 1)];
            }
            int gj = gj0 + j0l + d;
            int cw = min(gj + R, WW - 1) - max(gj - R, 0) + 1;
            ov[d] = fabsf(racc / (float)(ch * cw));
        }
        float4* d4 = (float4*)&dst[pbase + (size_t)i * WW + gj0 + j0l];
        d4[0] = make_float4(ov[0], ov[1], ov[2], ov[3]);
        d4[1] = make_float4(ov[4], ov[5], ov[6], ov[7]);
    }
}

// ---------------- dual-input avg pool + combining epilogue (tiled) ----------------
// v1 = avg(s1), v2 = avg(s2).
// EPI 1 (gn1): out = (|e1| - v2)/(|v1 - v2| + 1e-4)               [e1 = g]
// EPI 2 (map): out = ((e1 - v2)/(|v1 - v2| + 1e-4) + 0.01) * e2   [e1 = go, e2 = gn1]
template <int R, int EPI>
__global__ __launch_bounds__(256) void davg_pool(const float* __restrict__ s1,
                                                 const float* __restrict__ s2,
                                                 const float* __restrict__ e1,
                                                 const float* __restrict__ e2,
                                                 float* __restrict__ dst) {
    constexpr int TILESV = HH / TH, TILESH = WW / TW;
    constexpr int LW = TW + 2 * R;
    constexpr int PADL = LW + LW / 8 + 2;
    constexpr int NL2 = LW / 2;
    __shared__ float l1[TH * PADL], l2[TH * PADL];

    const int plane = blockIdx.x / (TILESV * TILESH);
    const int rem   = blockIdx.x % (TILESV * TILESH);
    const int i0    = (rem / TILESH) * TH;
    const int gj0   = (rem % TILESH) * TW;
    const size_t pbase = (size_t)plane * SS;
    const float* sp1 = s1 + pbase;
    const float* sp2 = s2 + pbase;
    const int t = threadIdx.x;

    if (t < NL2) {
        const int lj = 2 * t;
        const int gj = gj0 - R + lj;
        const bool cin = (unsigned)gj < (unsigned)WW;
        auto ld = [&](const float* sp, int gi) -> float2 {
            if (cin && (unsigned)gi < (unsigned)HH)
                return *(const float2*)(sp + (size_t)gi * WW + gj);
            return make_float2(0.f, 0.f);
        };
        float2 a1 = make_float2(0.f, 0.f), a2 = make_float2(0.f, 0.f);
        #pragma unroll
        for (int k = -R; k <= R; ++k) {
            float2 v = ld(sp1, i0 + k); a1.x += v.x; a1.y += v.y;
            float2 w = ld(sp2, i0 + k); a2.x += w.x; a2.y += w.y;
        }
        const int ca = lswz(lj);
        l1[ca] = a1.x; l1[ca + 1] = a1.y;
        l2[ca] = a2.x; l2[ca + 1] = a2.y;
        #pragma unroll
        for (int oi = 1; oi < TH; ++oi) {
            float2 p = ld(sp1, i0 + oi + R), q = ld(sp1, i0 + oi - R - 1);
            a1.x += p.x - q.x; a1.y += p.y - q.y;
            float2 u = ld(sp2, i0 + oi + R), w = ld(sp2, i0 + oi - R - 1);
            a2.x += u.x - w.x; a2.y += u.y - w.y;
            l1[oi * PADL + ca] = a1.x; l1[oi * PADL + ca + 1] = a1.y;
            l2[oi * PADL + ca] = a2.x; l2[oi * PADL + ca + 1] = a2.y;
        }
    }
    __syncthreads();

    for (int s = t; s < TH * (TW / 8); s += 256) {
        int rr = s >> 5, j0l = (s & 31) << 3;
        int i = i0 + rr;
        int ch = min(i + R, HH - 1) - max(i - R, 0) + 1;
        const float* r1 = &l1[rr * PADL];
        const float* r2 = &l2[rr * PADL];
        size_t rowbase = pbase + (size_t)i * WW + gj0 + j0l;

        float e1v[8], e2v[8];
        {
            float4 a0 = ((const float4*)(e1 + rowbase))[0];
            float4 a1q = ((const float4*)(e1 + rowbase))[1];
            e1v[0]=a0.x; e1v[1]=a0.y; e1v[2]=a0.z; e1v[3]=a0.w;
            e1v[4]=a1q.x; e1v[5]=a1q.y; e1v[6]=a1q.z; e1v[7]=a1q.w;
        }
        if (EPI == 2) {
            float4 b0 = ((const float4*)(e2 + rowbase))[0];
            float4 b1q = ((const float4*)(e2 + rowbase))[1];
            e2v[0]=b0.x; e2v[1]=b0.y; e2v[2]=b0.z; e2v[3]=b0.w;
            e2v[4]=b1q.x; e2v[5]=b1q.y; e2v[6]=b1q.z; e2v[7]=b1q.w;
        }

        float racc1 = 0.f, racc2 = 0.f;
        #pragma unroll
        for (int k = 0; k <= 2 * R; ++k) {
            int lc = lswz(j0l + k);
            racc1 += r1[lc]; racc2 += r2[lc];
        }
        float ov[8];
        #pragma unroll
        for (int d = 0; d < 8; ++d) {
            if (d > 0) {
                int la = lswz(j0l + d + 2 * R), lb = lswz(j0l + d - 1);
                racc1 += r1[la]; racc2 += r2[la];
                racc1 -= r1[lb]; racc2 -= r2[lb];
            }
            int gj = gj0 + j0l + d;
            float inv = 1.f / (float)(ch * (min(gj + R, WW - 1) - max(gj - R, 0) + 1));
            float v1 = racc1 * inv, v2 = racc2 * inv;
            float den = fabsf(v1 - v2) + 1e-4f;
            if (EPI == 1) ov[d] = (fabsf(e1v[d]) - v2) / den;
            else          ov[d] = ((e1v[d] - v2) / den + 0.01f) * e2v[d];
        }
        float4* d4 = (float4*)&dst[rowbase];
        d4[0] = make_float4(ov[0], ov[1], ov[2], ov[3]);
        d4[1] = make_float4(ov[4], ov[5], ov[6], ov[7]);
    }
}

// ---------------- reduction ----------------
// Layout: maps stacked as [seg0_a(16 planes) | seg0_b | seg1_a | seg1_b | ...].
// Element i pairs M[seg*2^23 + off] (a) with M[seg*2^23 + off + 2^22] (b),
// seg = i>>22, off = i & (2^22-1). Works for n = 2^22 (seg=0 only) and 2^23.
__global__ __launch_bounds__(256) void reduce1(const float* __restrict__ M,
                                               float* __restrict__ partials, int n4) {
    int tid = blockIdx.x * 256 + threadIdx.x;
    float v = 0.f;
    for (int q = tid; q < n4; q += 256 * 1024) {
        int i = q << 2;
        int seg = i >> 22;
        int off = i & ((1 << 22) - 1);
        size_t aidx = ((size_t)seg << 23) + (size_t)off;
        float4 a = *(const float4*)(M + aidx);
        float4 b = *(const float4*)(M + aidx + (1u << 22));
        v += a.x * expf(-10.f * (a.x + b.x));
        v += a.y * expf(-10.f * (a.y + b.y));
        v += a.z * expf(-10.f * (a.z + b.z));
        v += a.w * expf(-10.f * (a.w + b.w));
    }
    for (int off = 32; off; off >>= 1) v += __shfl_down(v, off);
    __shared__ float lds[4];
    int lane = threadIdx.x & 63, wv = threadIdx.x >> 6;
    if (lane == 0) lds[wv] = v;
    __syncthreads();
    if (threadIdx.x == 0) partials[blockIdx.x] = lds[0] + lds[1] + lds[2] + lds[3];
}

__global__ __launch_bounds__(256) void reduce2(const float* __restrict__ partials,
                                               float* __restrict__ out, float scale, int n) {
    float v = 0.f;
    for (int i = threadIdx.x; i < n; i += 256) v += partials[i];
    for (int off = 32; off; off >>= 1) v += __shfl_down(v, off);
    __shared__ float lds[4];
    int lane = threadIdx.x & 63, wv = threadIdx.x >> 6;
    if (lane == 0) lds[wv] = v;
    __syncthreads();
    if (threadIdx.x == 0) atomicAdd(out, (lds[0] + lds[1] + lds[2] + lds[3]) * scale);
}

// ---------------- host orchestration ----------------

// Pool pipeline over `planes` stacked planes. G holds g; map ends in A.
static void pool_pipeline(float* G, float* A, float* B, float* C, int planes, hipStream_t s) {
    int gp = planes * (HH / TH) * (WW / TW);
    dual_pool<true , 4><<<gp, 256, 0, s>>>(G, A, B);                 // A=max9|g|, B=min9|g|
    davg_pool<8, 1><<<gp, 256, 0, s>>>(A, B, G, nullptr, C);         // C=gn1
    avg_abs_pool<2><<<gp, 256, 0, s>>>(G, A);                        // A=go
    dual_pool<false, 3><<<gp, 256, 0, s>>>(A, B, G);                 // B=max7, G=min7
    davg_pool<3, 2><<<gp, 256, 0, s>>>(B, G, A, C, A);               // A=map
}

extern "C" void kernel_launch(void* const* d_in, const int* in_sizes, int n_in,
                              void* d_out, int out_size, void* d_ws, size_t ws_size,
                              hipStream_t stream) {
    const float* Rrgb = (const float*)d_in[0];
    const float* Lrgb = (const float*)d_in[1];
    float* out = (float*)d_out;
    float* w = (float*)d_ws;
    const float scale = 1.f / (float)P16N;
    const int gradblk = (P16N / 4 + 255) / 256;

    hipMemsetAsync(out, 0, sizeof(float) * (size_t)out_size, stream);

    const size_t stack64 = (size_t)64 * SS;
    if (ws_size >= 4 * stack64 * sizeof(float)) {
        // 4 buffers of 64 planes: layout [0..16)=Rgx [16..32)=Lgx [32..48)=Rgy [48..64)=Lgy
        float* G = w;
        float* A = G + stack64;
        float* B = A + stack64;
        float* C = B + stack64;
        grad_both<<<gradblk, 256, 0, stream>>>(Rrgb, G, 0, 32, 2);
        grad_both<<<gradblk, 256, 0, stream>>>(Lrgb, G, 16, 48, 2);
        pool_pipeline(G, A, B, C, 64, stream);
        float* partials = C;                      // C dead after final map
        reduce1<<<1024, 256, 0, stream>>>(A, partials, (2 * P16N) / 4);
        reduce2<<<1, 256, 0, stream>>>(partials, out, scale, 1024);
    } else {
        // fallback: 4 buffers of 32 planes (134 MB), one direction at a time
        const size_t stack32 = (size_t)32 * SS;
        float* G = w;
        float* A = G + stack32;
        float* B = A + stack32;
        float* C = B + stack32;
        for (int dir = 0; dir < 2; ++dir) {
            grad_both<<<gradblk, 256, 0, stream>>>(Rrgb, G, 0, 0, dir);
            grad_both<<<gradblk, 256, 0, stream>>>(Lrgb, G, 16, 16, dir);
            pool_pipeline(G, A, B, C, 32, stream);
            float* partials = C;
            reduce1<<<1024, 256, 0, stream>>>(A, partials, P16N / 4);
            reduce2<<<1, 256, 0, stream>>>(partials, out, scale, 1024);
        }
    }
}